// Round 11
// baseline (644.014 us; speedup 1.0000x reference)
//
#include <hip/hip_runtime.h>
#include <math.h>

#define NIMG 128
#define HW   256
#define NPX  (HW*HW)
#define NBLK (NIMG*16)   // 2048 blocks: (img, strip)

typedef float f32x4 __attribute__((ext_vector_type(4)));
typedef short bf16x8 __attribute__((ext_vector_type(8)));

__device__ __forceinline__ int refl_idx(int t) {
  return t < 0 ? -t : (t > 255 ? 510 - t : t);
}
__device__ __forceinline__ unsigned int bf16_rtn(float f) {
  unsigned int u = __float_as_uint(f);
  return (u + 0x7fffu + ((u >> 16) & 1u)) >> 16;
}
__device__ __forceinline__ unsigned int rtn_pack(float a, float b) {
  return bf16_rtn(a) | (bf16_rtn(b) << 16);
}
__device__ __forceinline__ unsigned int rhu_pack(float a, float b) {
  return ((__float_as_uint(a) + 0x8000u) >> 16) |
         ((__float_as_uint(b) + 0x8000u) & 0xffff0000u);
}
__device__ __forceinline__ unsigned short bf16_rhu(float a) {
  return (unsigned short)((__float_as_uint(a) + 0x8000u) >> 16);
}

// ---------------- Kernel A: per-image mean / inv_std (ddof=1) ----------------
__global__ __launch_bounds__(256)
void stats_kernel(const float* __restrict__ pred, const float* __restrict__ targ,
                  float* __restrict__ stats)
{
  const int b = blockIdx.x;
  const int which = b >> 7;
  const int img = b & 127;
  const float4* src = (const float4*)((which ? targ : pred) + (size_t)img * NPX);
  const int t = threadIdx.x;
  double s = 0.0, s2 = 0.0;
  for (int i = t; i < NPX/4; i += 256) {
    float4 v = src[i];
    s  += (double)v.x + (double)v.y + (double)v.z + (double)v.w;
    s2 += (double)v.x*v.x + (double)v.y*v.y + (double)v.z*v.z + (double)v.w*v.w;
  }
  __shared__ double rs[256], rs2[256];
  rs[t] = s; rs2[t] = s2;
  __syncthreads();
  for (int off = 128; off > 0; off >>= 1) {
    if (t < off) { rs[t] += rs[t+off]; rs2[t] += rs2[t+off]; }
    __syncthreads();
  }
  if (t == 0) {
    const double n = (double)NPX;
    double mean = rs[0] / n;
    double var = (rs2[0] - n*mean*mean) / (n - 1.0);
    stats[(which*NIMG + img)*2 + 0] = (float)mean;
    stats[(which*NIMG + img)*2 + 1] = (float)(1.0 / sqrt(var));
  }
}

// ---------------- Fused SSIM kernel: all 25 combos per block ----------------
// Block = (img, 16-row strip). 1024 threads = 16 waves. All LDS traffic on
// the combo path is ds_read_b128:
//  fields[5][col 272][20]: col-major k-pairs; col stride 80B (16B-aligned),
//    20 words -> lane-stride%8==4 -> 2-way banks (free). Vertical B = 1 b128/field.
//  vfT[5][16][296] u16, col vc at slot vc+6: window base 16B-aligned; row
//    stride 148 words%8==4 -> 2-way banks. Horizontal B = 1 b128/field.
// LDS 156.9KB -> 1 block/CU. red aliases vfT after the combo loop.
struct SMEM {
  unsigned int  fields[5][272][20];   // 108800 B
  unsigned short vfT[5][16][296];     //  47360 B
  unsigned short gwb[25][16];         //    800 B
};

__global__ __launch_bounds__(1024, 4)
void ssim_fused(const float* __restrict__ pred, const float* __restrict__ targ,
                const float* __restrict__ stats, float* __restrict__ partial)
{
  __shared__ SMEM sm;
  const int bid = blockIdx.x;
  const int img = bid >> 4, strip = bid & 15;
  const int R0 = strip * 16;
  const int t = threadIdx.x;
  const int lane = t & 63, wid = t >> 6;   // 16 waves
  const int g = lane >> 4;        // k-group 0..3
  const int mrow = lane & 15;     // A-row / B-col lane index

  // --- phase 0: all 25 combos' bf16 weight taps (double math, numpy-matching) ---
  if (t < 400) {
    const int c = t >> 4, tap = t & 15;
    const int ksi = c / 5, si = c % 5;
    const int ks = 5 + 2*ksi, PAD = 2 + ksi;
    const double sig = (si==0)?0.8:(si==1)?1.2:(si==2)?1.5:(si==3)?1.8:2.0;
    unsigned short w = 0;
    if (tap < ks) {
      double sum = 0.0, mine = 0.0;
      for (int a = 0; a < ks; ++a) {
        double d = (double)(a - PAD) / sig;
        double e = exp(-0.5 * d * d);
        sum += e;
        if (a == tap) mine = e;
      }
      w = (unsigned short)bf16_rtn((float)(mine / sum));
    }
    sm.gwb[c][tap] = w;
  }

  // --- phase 1: stage fields (32 reflected rows as 16 k-pairs, cols -8..263) ---
  const float mx  = stats[img*2 + 0];
  const float ixv = stats[img*2 + 1];
  const float my  = stats[(NIMG + img)*2 + 0];
  const float iyv = stats[(NIMG + img)*2 + 1];
  const float4* p4 = (const float4*)(pred + (size_t)img * NPX);
  const float4* t4 = (const float4*)(targ + (size_t)img * NPX);

  {
    const int k2 = t & 15, c4 = t >> 4;       // 16 k-pairs x 64 col-quads
    const int gr0 = refl_idx(R0 - 6 + 2*k2);
    const int gr1 = refl_idx(R0 - 6 + 2*k2 + 1);
    float4 pa = p4[gr0*64 + c4], pb = p4[gr1*64 + c4];
    float4 ta = t4[gr0*64 + c4], tb = t4[gr1*64 + c4];
    const int pc = 8 + c4*4;
    {
      float xa=(pa.x-mx)*ixv, xb=(pb.x-mx)*ixv, ya=(ta.x-my)*iyv, yb=(tb.x-my)*iyv;
      sm.fields[0][pc+0][k2] = rtn_pack(xa, xb);
      sm.fields[1][pc+0][k2] = rtn_pack(ya, yb);
      sm.fields[2][pc+0][k2] = rhu_pack(xa*xa, xb*xb);
      sm.fields[3][pc+0][k2] = rhu_pack(ya*ya, yb*yb);
      sm.fields[4][pc+0][k2] = rhu_pack(xa*ya, xb*yb);
    }
    {
      float xa=(pa.y-mx)*ixv, xb=(pb.y-mx)*ixv, ya=(ta.y-my)*iyv, yb=(tb.y-my)*iyv;
      sm.fields[0][pc+1][k2] = rtn_pack(xa, xb);
      sm.fields[1][pc+1][k2] = rtn_pack(ya, yb);
      sm.fields[2][pc+1][k2] = rhu_pack(xa*xa, xb*xb);
      sm.fields[3][pc+1][k2] = rhu_pack(ya*ya, yb*yb);
      sm.fields[4][pc+1][k2] = rhu_pack(xa*ya, xb*yb);
    }
    {
      float xa=(pa.z-mx)*ixv, xb=(pb.z-mx)*ixv, ya=(ta.z-my)*iyv, yb=(tb.z-my)*iyv;
      sm.fields[0][pc+2][k2] = rtn_pack(xa, xb);
      sm.fields[1][pc+2][k2] = rtn_pack(ya, yb);
      sm.fields[2][pc+2][k2] = rhu_pack(xa*xa, xb*xb);
      sm.fields[3][pc+2][k2] = rhu_pack(ya*ya, yb*yb);
      sm.fields[4][pc+2][k2] = rhu_pack(xa*ya, xb*yb);
    }
    {
      float xa=(pa.w-mx)*ixv, xb=(pb.w-mx)*ixv, ya=(ta.w-my)*iyv, yb=(tb.w-my)*iyv;
      sm.fields[0][pc+3][k2] = rtn_pack(xa, xb);
      sm.fields[1][pc+3][k2] = rtn_pack(ya, yb);
      sm.fields[2][pc+3][k2] = rhu_pack(xa*xa, xb*xb);
      sm.fields[3][pc+3][k2] = rhu_pack(ya*ya, yb*yb);
      sm.fields[4][pc+3][k2] = rhu_pack(xa*ya, xb*yb);
    }
  }
  // reflect-pad columns (pc 0..7 and 264..271)
  if (t < 256) {
    const int k2 = t & 15, jj = t >> 4;
    const int pc = (jj < 8) ? jj : 256 + jj;
    const int ric = refl_idx(pc - 8);
    const int gr0 = refl_idx(R0 - 6 + 2*k2);
    const int gr1 = refl_idx(R0 - 6 + 2*k2 + 1);
    const float* pp = pred + (size_t)img * NPX;
    const float* tp = targ + (size_t)img * NPX;
    float xa = (pp[gr0*HW + ric] - mx)*ixv, xb = (pp[gr1*HW + ric] - mx)*ixv;
    float ya = (tp[gr0*HW + ric] - my)*iyv, yb = (tp[gr1*HW + ric] - my)*iyv;
    sm.fields[0][pc][k2] = rtn_pack(xa, xb);
    sm.fields[1][pc][k2] = rtn_pack(ya, yb);
    sm.fields[2][pc][k2] = rhu_pack(xa*xa, xb*xb);
    sm.fields[3][pc][k2] = rhu_pack(ya*ya, yb*yb);
    sm.fields[4][pc][k2] = rhu_pack(xa*ya, xb*yb);
  }
  // zero vfT tail slots 278..295 for ALL 80 rows (1440 items > 1024 threads:
  // MUST be strided — round-10 bug was `if (t < 1440)` leaving rows 57..79
  // as garbage; 0 x NaN = NaN through the MFMA)
  for (int i = t; i < 80*18; i += 1024) {
    const int rw = i / 18, s6 = i % 18;
    (&sm.vfT[0][0][0])[rw*296 + 278 + s6] = 0;
  }

  union UF { unsigned int w[4]; bf16x8 v; };
  const f32x4 zero4 = {0.f, 0.f, 0.f, 0.f};
  const float C1f = 1e-4f, C2f = 9e-4f;
  float acc_total = 0.f;
  const int r = R0 + mrow;

  for (int cb = 0; cb < 25; ++cb) {
    const int ksi = cb / 5;
    const int PAD = 2 + ksi;

    __syncthreads();   // cb==0: staging visible; cb>0: prev horizontal reads done

    // A fragment: A[m][k] = g[k - m - 6 + PAD] (shared by both passes)
    UF ua_;
    #pragma unroll
    for (int j2 = 0; j2 < 4; ++j2) {
      const int d0 = g*8 + 2*j2 - mrow - 6 + PAD;
      const unsigned int w0 = ((unsigned)d0 < 16u) ? (unsigned)sm.gwb[cb][d0] : 0u;
      const unsigned int w1 = ((unsigned)(d0+1) < 16u) ? (unsigned)sm.gwb[cb][d0+1] : 0u;
      ua_.w[j2] = w0 | (w1 << 16);
    }
    const bf16x8 afrag = ua_.v;

    // vertical pass: 17 col-tiles over 16 waves; B = 1 b128 per field
    for (int tau = wid; tau < 17; tau += 16) {
      const int vc = tau*16 + mrow;
      UF bx, by, bxx, byy, bxy;
      *(uint4*)bx.w  = *(const uint4*)&sm.fields[0][vc][g*4];
      *(uint4*)by.w  = *(const uint4*)&sm.fields[1][vc][g*4];
      *(uint4*)bxx.w = *(const uint4*)&sm.fields[2][vc][g*4];
      *(uint4*)byy.w = *(const uint4*)&sm.fields[3][vc][g*4];
      *(uint4*)bxy.w = *(const uint4*)&sm.fields[4][vc][g*4];
      f32x4 dx  = __builtin_amdgcn_mfma_f32_16x16x32_bf16(afrag, bx.v,  zero4, 0,0,0);
      f32x4 dy  = __builtin_amdgcn_mfma_f32_16x16x32_bf16(afrag, by.v,  zero4, 0,0,0);
      f32x4 dxx = __builtin_amdgcn_mfma_f32_16x16x32_bf16(afrag, bxx.v, zero4, 0,0,0);
      f32x4 dyy = __builtin_amdgcn_mfma_f32_16x16x32_bf16(afrag, byy.v, zero4, 0,0,0);
      f32x4 dxy = __builtin_amdgcn_mfma_f32_16x16x32_bf16(afrag, bxy.v, zero4, 0,0,0);
      #pragma unroll
      for (int i = 0; i < 4; ++i) {
        const int row = g*4 + i;
        sm.vfT[0][row][vc + 6] = bf16_rhu(dx[i]);
        sm.vfT[1][row][vc + 6] = bf16_rhu(dy[i]);
        sm.vfT[2][row][vc + 6] = bf16_rhu(dxx[i]);
        sm.vfT[3][row][vc + 6] = bf16_rhu(dyy[i]);
        sm.vfT[4][row][vc + 6] = bf16_rhu(dxy[i]);
      }
    }
    __syncthreads();

    // horizontal pass + smap: one 16-col tile per wave; B = 1 b128 per field
    {
      const unsigned int* vfT32 = (const unsigned int*)sm.vfT;
      const bool rok = (r >= PAD) && (r < HW - PAD);
      float accc = 0.f;
      const int ht = wid;
      const int C0 = ht*16;
      const int w0 = mrow*148 + 8*ht + 4 + 4*g;   // +f*2368 per field
      UF bx, by, bxx, byy, bxy;
      *(uint4*)bx.w  = *(const uint4*)&vfT32[w0];
      *(uint4*)by.w  = *(const uint4*)&vfT32[w0 + 2368];
      *(uint4*)bxx.w = *(const uint4*)&vfT32[w0 + 2*2368];
      *(uint4*)byy.w = *(const uint4*)&vfT32[w0 + 3*2368];
      *(uint4*)bxy.w = *(const uint4*)&vfT32[w0 + 4*2368];
      f32x4 dhx  = __builtin_amdgcn_mfma_f32_16x16x32_bf16(afrag, bx.v,  zero4, 0,0,0);
      f32x4 dhy  = __builtin_amdgcn_mfma_f32_16x16x32_bf16(afrag, by.v,  zero4, 0,0,0);
      f32x4 dhxx = __builtin_amdgcn_mfma_f32_16x16x32_bf16(afrag, bxx.v, zero4, 0,0,0);
      f32x4 dhyy = __builtin_amdgcn_mfma_f32_16x16x32_bf16(afrag, byy.v, zero4, 0,0,0);
      f32x4 dhxy = __builtin_amdgcn_mfma_f32_16x16x32_bf16(afrag, bxy.v, zero4, 0,0,0);
      #pragma unroll
      for (int i = 0; i < 4; ++i) {
        const int c = C0 + g*4 + i;
        if (rok && c >= PAD && c < HW - PAD) {
          const float hx = dhx[i], hy = dhy[i];
          const float hxx = dhxx[i], hyy = dhyy[i], hxy = dhxy[i];
          const float sx = hxx - hx*hx, sy = hyy - hy*hy, sxy = hxy - hx*hy;
          const float num = (2.f*hx*hy + C1f) * (2.f*sxy + C2f);
          const float den = (hx*hx + hy*hy + C1f) * (sx + sy + C2f);
          accc += num * __builtin_amdgcn_rcpf(den);
        }
      }
      const float n1 = (float)(HW - 2*PAD);
      acc_total += accc * __builtin_amdgcn_rcpf(n1 * n1);
    }
  }

  // block reduction (red aliases vfT; all vfT reads are done)
  __syncthreads();
  float* red = (float*)&sm.vfT[0][0][0];
  red[t] = acc_total;
  __syncthreads();
  for (int off = 512; off > 0; off >>= 1) {
    if (t < off) red[t] += red[t+off];
    __syncthreads();
  }
  if (t == 0) partial[bid] = red[0] * (1.f / (25.f * 128.f));
}

// ---------------- Kernel C: final deterministic reduction ----------------
__global__ __launch_bounds__(256)
void reduce_kernel(const float* __restrict__ partial, float* __restrict__ out)
{
  const int t = threadIdx.x;
  double s = 0.0;
  for (int i = t; i < NBLK; i += 256) s += (double)partial[i];
  __shared__ double red[256];
  red[t] = s;
  __syncthreads();
  for (int off = 128; off > 0; off >>= 1) {
    if (t < off) red[t] += red[t+off];
    __syncthreads();
  }
  if (t == 0) out[0] = (float)(0.5 - 0.5 * red[0]);
}

extern "C" void kernel_launch(void* const* d_in, const int* in_sizes, int n_in,
                              void* d_out, int out_size, void* d_ws, size_t ws_size,
                              hipStream_t stream) {
  const float* pred = (const float*)d_in[0];
  const float* targ = (const float*)d_in[1];
  float* out = (float*)d_out;
  float* ws = (float*)d_ws;
  float* stats   = ws;          // 512 floats
  float* partial = ws + 512;    // NBLK floats

  stats_kernel<<<256, 256, 0, stream>>>(pred, targ, stats);
  ssim_fused<<<NBLK, 1024, 0, stream>>>(pred, targ, stats, partial);
  reduce_kernel<<<1, 256, 0, stream>>>(partial, out);
}

// Round 14
// 472.957 us; speedup vs baseline: 1.3617x; 1.3617x over previous
//
#include <hip/hip_runtime.h>
#include <math.h>

#define NIMG 128
#define HW   256
#define NPX  (HW*HW)
#define NBLK (NIMG*16)   // 2048 blocks: (img, strip)

typedef float f32x4 __attribute__((ext_vector_type(4)));
typedef short bf16x8 __attribute__((ext_vector_type(8)));

__device__ __forceinline__ int refl_idx(int t) {
  return t < 0 ? -t : (t > 255 ? 510 - t : t);
}
__device__ __forceinline__ unsigned int bf16_rtn(float f) {
  unsigned int u = __float_as_uint(f);
  return (u + 0x7fffu + ((u >> 16) & 1u)) >> 16;
}
__device__ __forceinline__ unsigned int rtn_pack(float a, float b) {
  return bf16_rtn(a) | (bf16_rtn(b) << 16);
}
__device__ __forceinline__ unsigned int rhu_pack(float a, float b) {
  return ((__float_as_uint(a) + 0x8000u) >> 16) |
         ((__float_as_uint(b) + 0x8000u) & 0xffff0000u);
}
__device__ __forceinline__ unsigned short bf16_rhu(float a) {
  return (unsigned short)((__float_as_uint(a) + 0x8000u) >> 16);
}

// ---------------- Kernel A: per-image mean / inv_std (ddof=1) ----------------
__global__ __launch_bounds__(256)
void stats_kernel(const float* __restrict__ pred, const float* __restrict__ targ,
                  float* __restrict__ stats)
{
  const int b = blockIdx.x;
  const int which = b >> 7;
  const int img = b & 127;
  const float4* src = (const float4*)((which ? targ : pred) + (size_t)img * NPX);
  const int t = threadIdx.x;
  double s = 0.0, s2 = 0.0;
  for (int i = t; i < NPX/4; i += 256) {
    float4 v = src[i];
    s  += (double)v.x + (double)v.y + (double)v.z + (double)v.w;
    s2 += (double)v.x*v.x + (double)v.y*v.y + (double)v.z*v.z + (double)v.w*v.w;
  }
  __shared__ double rs[256], rs2[256];
  rs[t] = s; rs2[t] = s2;
  __syncthreads();
  for (int off = 128; off > 0; off >>= 1) {
    if (t < off) { rs[t] += rs[t+off]; rs2[t] += rs2[t+off]; }
    __syncthreads();
  }
  if (t == 0) {
    const double n = (double)NPX;
    double mean = rs[0] / n;
    double var = (rs2[0] - n*mean*mean) / (n - 1.0);
    stats[(which*NIMG + img)*2 + 0] = (float)mean;
    stats[(which*NIMG + img)*2 + 1] = (float)(1.0 / sqrt(var));
  }
}

// ---------------- Fused SSIM kernel: all 25 combos per block ----------------
// Block = (img, 16-row strip). 1024 threads = 16 waves.
// Round-9 structure, with ONE change: vertical B-fragments (combo-invariant)
// are hoisted into REGISTERS once per block via direct global loads — the
// fields LDS buffer and all vertical-pass LDS reads (340 instr/combo) vanish.
// vfT layout + horizontal pass + epilogue are round-9 verbatim (verified).
struct SMEM {
  unsigned short vfT[5*16*282];   // 45120 B: vertical-blur out, bf16 [f][row][col]
  unsigned short gwb[25][16];     //   800 B: bf16 gaussian taps per combo
  float red[1024];                //  4096 B
};

__global__ __launch_bounds__(1024, 4)
void ssim_fused(const float* __restrict__ pred, const float* __restrict__ targ,
                const float* __restrict__ stats, float* __restrict__ partial)
{
  __shared__ SMEM sm;
  const int bid = blockIdx.x;
  const int img = bid >> 4, strip = bid & 15;
  const int R0 = strip * 16;
  const int t = threadIdx.x;
  const int lane = t & 63, wid = t >> 6;   // 16 waves
  const int g = lane >> 4;        // k-group 0..3
  const int mrow = lane & 15;     // A-row / B-col lane index

  // --- phase 0: all 25 combos' bf16 weight taps (double math, numpy-matching) ---
  if (t < 400) {
    const int c = t >> 4, tap = t & 15;
    const int ksi = c / 5, si = c % 5;
    const int ks = 5 + 2*ksi, PAD = 2 + ksi;
    const double sig = (si==0)?0.8:(si==1)?1.2:(si==2)?1.5:(si==3)?1.8:2.0;
    unsigned short w = 0;
    if (tap < ks) {
      double sum = 0.0, mine = 0.0;
      for (int a = 0; a < ks; ++a) {
        double d = (double)(a - PAD) / sig;
        double e = exp(-0.5 * d * d);
        sum += e;
        if (a == tap) mine = e;
      }
      w = (unsigned short)bf16_rtn((float)(mine / sum));
    }
    sm.gwb[c][tap] = w;
  }
  // zero vfT tail slots 272..281 of each of 80 rows (horizontal window
  // over-reads them with zero weight; must be non-NaN). 800 items, single shot.
  if (t < 800) {
    sm.vfT[(t/10)*282 + 272 + (t%10)] = 0;
  }

  // --- phase 1: hoist vertical B-fragments into registers (once per block) ---
  const float mx  = stats[img*2 + 0];
  const float ixv = stats[img*2 + 1];
  const float my  = stats[(NIMG + img)*2 + 0];
  const float iyv = stats[(NIMG + img)*2 + 1];
  const float* pp = pred + (size_t)img * NPX;
  const float* tp = targ + (size_t)img * NPX;

  union UF { unsigned int w[4]; bf16x8 v; };
  UF aX{}, aY{}, aXX{}, aYY{}, aXY{};   // tile tau = wid  (all waves)
  UF bX{}, bY{}, bXX{}, bYY{}, bXY{};   // tile tau = 16   (wave 0 only)

  auto stage_tile = [&](int tau, UF& fx, UF& fy, UF& fxx, UF& fyy, UF& fxy) {
    const int ci = refl_idx(tau*16 + mrow - 8);     // image col (reflect)
    #pragma unroll
    for (int j2 = 0; j2 < 4; ++j2) {
      const int k0  = 8*g + 2*j2;                   // staged-row pair
      const int ar0 = refl_idx(R0 - 6 + k0);
      const int ar1 = refl_idx(R0 - 5 + k0);
      const float p0 = pp[ar0*HW + ci], p1 = pp[ar1*HW + ci];
      const float q0 = tp[ar0*HW + ci], q1 = tp[ar1*HW + ci];
      const float xa = (p0 - mx)*ixv, xb = (p1 - mx)*ixv;
      const float ya = (q0 - my)*iyv, yb = (q1 - my)*iyv;
      fx.w[j2]  = rtn_pack(xa, xb);
      fy.w[j2]  = rtn_pack(ya, yb);
      fxx.w[j2] = rhu_pack(xa*xa, xb*xb);
      fyy.w[j2] = rhu_pack(ya*ya, yb*yb);
      fxy.w[j2] = rhu_pack(xa*ya, xb*yb);
    }
  };
  stage_tile(wid, aX, aY, aXX, aYY, aXY);
  if (wid == 0) stage_tile(16, bX, bY, bXX, bYY, bXY);

  const f32x4 zero4 = {0.f, 0.f, 0.f, 0.f};
  const float C1f = 1e-4f, C2f = 9e-4f;
  float acc_total = 0.f;
  const int r = R0 + mrow;

  for (int cb = 0; cb < 25; ++cb) {
    const int PAD = 2 + cb/5;

    __syncthreads();   // cb==0: gwb/vfT-tails visible; cb>0: prev horizontal done

    // weight A-fragment: A[m][k] = g[k - m - 6 + PAD] (shared by both passes)
    UF ua_;
    #pragma unroll
    for (int j2 = 0; j2 < 4; ++j2) {
      const int d0 = g*8 + 2*j2 - mrow - 6 + PAD;
      const unsigned int w0 = ((unsigned)d0 < 16u) ? (unsigned)sm.gwb[cb][d0] : 0u;
      const unsigned int w1 = ((unsigned)(d0+1) < 16u) ? (unsigned)sm.gwb[cb][d0+1] : 0u;
      ua_.w[j2] = w0 | (w1 << 16);
    }
    const bf16x8 afrag = ua_.v;

    // vertical pass: tile tau = wid, B straight from registers (no LDS reads)
    {
      const int vc = wid*16 + mrow;
      f32x4 dx  = __builtin_amdgcn_mfma_f32_16x16x32_bf16(afrag, aX.v,  zero4, 0,0,0);
      f32x4 dy  = __builtin_amdgcn_mfma_f32_16x16x32_bf16(afrag, aY.v,  zero4, 0,0,0);
      f32x4 dxx = __builtin_amdgcn_mfma_f32_16x16x32_bf16(afrag, aXX.v, zero4, 0,0,0);
      f32x4 dyy = __builtin_amdgcn_mfma_f32_16x16x32_bf16(afrag, aYY.v, zero4, 0,0,0);
      f32x4 dxy = __builtin_amdgcn_mfma_f32_16x16x32_bf16(afrag, aXY.v, zero4, 0,0,0);
      #pragma unroll
      for (int i = 0; i < 4; ++i) {
        const int rb = (g*4 + i)*282 + vc;
        sm.vfT[0*4512 + rb] = bf16_rhu(dx[i]);
        sm.vfT[1*4512 + rb] = bf16_rhu(dy[i]);
        sm.vfT[2*4512 + rb] = bf16_rhu(dxx[i]);
        sm.vfT[3*4512 + rb] = bf16_rhu(dyy[i]);
        sm.vfT[4*4512 + rb] = bf16_rhu(dxy[i]);
      }
    }
    if (wid == 0) {   // 17th tile (right pad cols 256..271)
      const int vc = 256 + mrow;
      f32x4 dx  = __builtin_amdgcn_mfma_f32_16x16x32_bf16(afrag, bX.v,  zero4, 0,0,0);
      f32x4 dy  = __builtin_amdgcn_mfma_f32_16x16x32_bf16(afrag, bY.v,  zero4, 0,0,0);
      f32x4 dxx = __builtin_amdgcn_mfma_f32_16x16x32_bf16(afrag, bXX.v, zero4, 0,0,0);
      f32x4 dyy = __builtin_amdgcn_mfma_f32_16x16x32_bf16(afrag, bYY.v, zero4, 0,0,0);
      f32x4 dxy = __builtin_amdgcn_mfma_f32_16x16x32_bf16(afrag, bXY.v, zero4, 0,0,0);
      #pragma unroll
      for (int i = 0; i < 4; ++i) {
        const int rb = (g*4 + i)*282 + vc;
        sm.vfT[0*4512 + rb] = bf16_rhu(dx[i]);
        sm.vfT[1*4512 + rb] = bf16_rhu(dy[i]);
        sm.vfT[2*4512 + rb] = bf16_rhu(dxx[i]);
        sm.vfT[3*4512 + rb] = bf16_rhu(dyy[i]);
        sm.vfT[4*4512 + rb] = bf16_rhu(dxy[i]);
      }
    }
    __syncthreads();

    // horizontal pass + smap: one 16-col tile per wave (round-9 verbatim)
    {
      const unsigned int* vfT32 = (const unsigned int*)sm.vfT;
      const bool rok = (r >= PAD) && (r < HW - PAD);
      float accc = 0.f;
      const int ht = wid;
      const int C0 = ht*16;
      const int w0 = mrow*141 + ((C0 + 2) >> 1) + g*4;
      UF bx, by, bxx, byy, bxy;
      #pragma unroll
      for (int j2 = 0; j2 < 4; ++j2) {
        bx.w[j2]  = vfT32[w0 + j2];
        by.w[j2]  = vfT32[w0 + j2 + 2256];
        bxx.w[j2] = vfT32[w0 + j2 + 2*2256];
        byy.w[j2] = vfT32[w0 + j2 + 3*2256];
        bxy.w[j2] = vfT32[w0 + j2 + 4*2256];
      }
      f32x4 dhx  = __builtin_amdgcn_mfma_f32_16x16x32_bf16(afrag, bx.v,  zero4, 0,0,0);
      f32x4 dhy  = __builtin_amdgcn_mfma_f32_16x16x32_bf16(afrag, by.v,  zero4, 0,0,0);
      f32x4 dhxx = __builtin_amdgcn_mfma_f32_16x16x32_bf16(afrag, bxx.v, zero4, 0,0,0);
      f32x4 dhyy = __builtin_amdgcn_mfma_f32_16x16x32_bf16(afrag, byy.v, zero4, 0,0,0);
      f32x4 dhxy = __builtin_amdgcn_mfma_f32_16x16x32_bf16(afrag, bxy.v, zero4, 0,0,0);
      #pragma unroll
      for (int i = 0; i < 4; ++i) {
        const int c = C0 + g*4 + i;
        if (rok && c >= PAD && c < HW - PAD) {
          const float hx = dhx[i], hy = dhy[i];
          const float hxx = dhxx[i], hyy = dhyy[i], hxy = dhxy[i];
          const float sx = hxx - hx*hx, sy = hyy - hy*hy, sxy = hxy - hx*hy;
          const float num = (2.f*hx*hy + C1f) * (2.f*sxy + C2f);
          const float den = (hx*hx + hy*hy + C1f) * (sx + sy + C2f);
          accc += num * __builtin_amdgcn_rcpf(den);
        }
      }
      const float n1 = (float)(HW - 2*PAD);
      acc_total += accc * __builtin_amdgcn_rcpf(n1 * n1);
    }
  }

  // block reduction
  __syncthreads();
  sm.red[t] = acc_total;
  __syncthreads();
  for (int off = 512; off > 0; off >>= 1) {
    if (t < off) sm.red[t] += sm.red[t+off];
    __syncthreads();
  }
  if (t == 0) partial[bid] = sm.red[0] * (1.f / (25.f * 128.f));
}

// ---------------- Kernel C: final deterministic reduction ----------------
__global__ __launch_bounds__(256)
void reduce_kernel(const float* __restrict__ partial, float* __restrict__ out)
{
  const int t = threadIdx.x;
  double s = 0.0;
  for (int i = t; i < NBLK; i += 256) s += (double)partial[i];
  __shared__ double red[256];
  red[t] = s;
  __syncthreads();
  for (int off = 128; off > 0; off >>= 1) {
    if (t < off) red[t] += red[t+off];
    __syncthreads();
  }
  if (t == 0) out[0] = (float)(0.5 - 0.5 * red[0]);
}

extern "C" void kernel_launch(void* const* d_in, const int* in_sizes, int n_in,
                              void* d_out, int out_size, void* d_ws, size_t ws_size,
                              hipStream_t stream) {
  const float* pred = (const float*)d_in[0];
  const float* targ = (const float*)d_in[1];
  float* out = (float*)d_out;
  float* ws = (float*)d_ws;
  float* stats   = ws;          // 512 floats
  float* partial = ws + 512;    // NBLK floats

  stats_kernel<<<256, 256, 0, stream>>>(pred, targ, stats);
  ssim_fused<<<NBLK, 1024, 0, stream>>>(pred, targ, stats, partial);
  reduce_kernel<<<1, 256, 0, stream>>>(partial, out);
}

// Round 15
// 425.332 us; speedup vs baseline: 1.5141x; 1.1120x over previous
//
#include <hip/hip_runtime.h>
#include <math.h>

#define NIMG 128
#define HW   256
#define NPX  (HW*HW)
#define NBLK (NIMG*16)   // 2048 blocks: (img, strip)

typedef float f32x4 __attribute__((ext_vector_type(4)));
typedef short bf16x8 __attribute__((ext_vector_type(8)));

__device__ __forceinline__ int refl_idx(int t) {
  return t < 0 ? -t : (t > 255 ? 510 - t : t);
}
__device__ __forceinline__ unsigned int bf16_rtn(float f) {
  unsigned int u = __float_as_uint(f);
  return (u + 0x7fffu + ((u >> 16) & 1u)) >> 16;
}
__device__ __forceinline__ unsigned int rtn_pack(float a, float b) {
  return bf16_rtn(a) | (bf16_rtn(b) << 16);
}
__device__ __forceinline__ unsigned int rhu_pack(float a, float b) {
  return ((__float_as_uint(a) + 0x8000u) >> 16) |
         ((__float_as_uint(b) + 0x8000u) & 0xffff0000u);
}

// ---------------- Kernel A: per-image mean / inv_std (ddof=1) ----------------
__global__ __launch_bounds__(256)
void stats_kernel(const float* __restrict__ pred, const float* __restrict__ targ,
                  float* __restrict__ stats)
{
  const int b = blockIdx.x;
  const int which = b >> 7;
  const int img = b & 127;
  const float4* src = (const float4*)((which ? targ : pred) + (size_t)img * NPX);
  const int t = threadIdx.x;
  double s = 0.0, s2 = 0.0;
  for (int i = t; i < NPX/4; i += 256) {
    float4 v = src[i];
    s  += (double)v.x + (double)v.y + (double)v.z + (double)v.w;
    s2 += (double)v.x*v.x + (double)v.y*v.y + (double)v.z*v.z + (double)v.w*v.w;
  }
  __shared__ double rs[256], rs2[256];
  rs[t] = s; rs2[t] = s2;
  __syncthreads();
  for (int off = 128; off > 0; off >>= 1) {
    if (t < off) { rs[t] += rs[t+off]; rs2[t] += rs2[t+off]; }
    __syncthreads();
  }
  if (t == 0) {
    const double n = (double)NPX;
    double mean = rs[0] / n;
    double var = (rs2[0] - n*mean*mean) / (n - 1.0);
    stats[(which*NIMG + img)*2 + 0] = (float)mean;
    stats[(which*NIMG + img)*2 + 1] = (float)(1.0 / sqrt(var));
  }
}

// ---------------- Fused SSIM kernel: all 25 combos per block ----------------
// Block = (img, 16-row strip). 1024 threads = 16 waves.
// Round-14 structure + ONE change: vertical MFMA computes the TRANSPOSED
// result via operand swap (mfma(field, W) instead of mfma(W, field); the
// banded weight fragment is identical in A- and B-roles). Each lane then
// holds row=mrow, 4 CONSECUTIVE columns -> vfT writes become 1 b64 per
// field (5 instead of 20 b16). Horizontal reads unchanged (row-major
// u32 col-pairs). Row stride 284 u16 (568 B, 8B-aligned rows).
struct SMEM {
  unsigned short vfT[5*16*284];   // 45440 B: [f][row][col], stride 284
  unsigned short gwb[25][16];     //   800 B: bf16 gaussian taps per combo
  float red[1024];                //  4096 B
};

__global__ __launch_bounds__(1024, 4)
void ssim_fused(const float* __restrict__ pred, const float* __restrict__ targ,
                const float* __restrict__ stats, float* __restrict__ partial)
{
  __shared__ SMEM sm;
  const int bid = blockIdx.x;
  const int img = bid >> 4, strip = bid & 15;
  const int R0 = strip * 16;
  const int t = threadIdx.x;
  const int lane = t & 63, wid = t >> 6;   // 16 waves
  const int g = lane >> 4;        // k-group 0..3
  const int mrow = lane & 15;     // A-row / B-col lane index

  // --- phase 0: all 25 combos' bf16 weight taps (double math, numpy-matching) ---
  if (t < 400) {
    const int c = t >> 4, tap = t & 15;
    const int ksi = c / 5, si = c % 5;
    const int ks = 5 + 2*ksi, PAD = 2 + ksi;
    const double sig = (si==0)?0.8:(si==1)?1.2:(si==2)?1.5:(si==3)?1.8:2.0;
    unsigned short w = 0;
    if (tap < ks) {
      double sum = 0.0, mine = 0.0;
      for (int a = 0; a < ks; ++a) {
        double d = (double)(a - PAD) / sig;
        double e = exp(-0.5 * d * d);
        sum += e;
        if (a == tap) mine = e;
      }
      w = (unsigned short)bf16_rtn((float)(mine / sum));
    }
    sm.gwb[c][tap] = w;
  }
  // zero vfT tail cols 272..283 of all 80 rows (horizontal window over-reads
  // them with zero weight; must be non-NaN). 960 items < 1024 threads.
  if (t < 960) {
    sm.vfT[(t/12)*284 + 272 + (t%12)] = 0;
  }

  // --- phase 1: hoist vertical fragments into registers (once per block) ---
  const float mx  = stats[img*2 + 0];
  const float ixv = stats[img*2 + 1];
  const float my  = stats[(NIMG + img)*2 + 0];
  const float iyv = stats[(NIMG + img)*2 + 1];
  const float* pp = pred + (size_t)img * NPX;
  const float* tp = targ + (size_t)img * NPX;

  union UF { unsigned int w[4]; bf16x8 v; };
  UF aX{}, aY{}, aXX{}, aYY{}, aXY{};   // tile tau = wid  (all waves)
  UF bX{}, bY{}, bXX{}, bYY{}, bXY{};   // tile tau = 16   (wave 0 only)

  auto stage_tile = [&](int tau, UF& fx, UF& fy, UF& fxx, UF& fyy, UF& fxy) {
    const int ci = refl_idx(tau*16 + mrow - 8);     // image col (reflect)
    #pragma unroll
    for (int j2 = 0; j2 < 4; ++j2) {
      const int k0  = 8*g + 2*j2;                   // staged-row pair
      const int ar0 = refl_idx(R0 - 6 + k0);
      const int ar1 = refl_idx(R0 - 5 + k0);
      const float p0 = pp[ar0*HW + ci], p1 = pp[ar1*HW + ci];
      const float q0 = tp[ar0*HW + ci], q1 = tp[ar1*HW + ci];
      const float xa = (p0 - mx)*ixv, xb = (p1 - mx)*ixv;
      const float ya = (q0 - my)*iyv, yb = (q1 - my)*iyv;
      fx.w[j2]  = rtn_pack(xa, xb);
      fy.w[j2]  = rtn_pack(ya, yb);
      fxx.w[j2] = rhu_pack(xa*xa, xb*xb);
      fyy.w[j2] = rhu_pack(ya*ya, yb*yb);
      fxy.w[j2] = rhu_pack(xa*ya, xb*yb);
    }
  };
  stage_tile(wid, aX, aY, aXX, aYY, aXY);
  if (wid == 0) stage_tile(16, bX, bY, bXX, bYY, bXY);

  const f32x4 zero4 = {0.f, 0.f, 0.f, 0.f};
  const float C1f = 1e-4f, C2f = 9e-4f;
  float acc_total = 0.f;
  const int r = R0 + mrow;

  for (int cb = 0; cb < 25; ++cb) {
    const int PAD = 2 + cb/5;

    __syncthreads();   // cb==0: gwb/vfT-tails visible; cb>0: prev horizontal done

    // weight fragment: W[m][k] = g[k - m - 6 + PAD]; identical in A- and
    // B-roles (band is d = k - row in both lane layouts)
    UF ua_;
    #pragma unroll
    for (int j2 = 0; j2 < 4; ++j2) {
      const int d0 = g*8 + 2*j2 - mrow - 6 + PAD;
      const unsigned int w0 = ((unsigned)d0 < 16u) ? (unsigned)sm.gwb[cb][d0] : 0u;
      const unsigned int w1 = ((unsigned)(d0+1) < 16u) ? (unsigned)sm.gwb[cb][d0+1] : 0u;
      ua_.w[j2] = w0 | (w1 << 16);
    }
    const bf16x8 afrag = ua_.v;

    // vertical pass (TRANSPOSED: field as A, W as B) -> lane holds row=mrow,
    // cols tile*16+g*4..+3 -> one b64 write per field
    {
      const int vc0 = wid*16 + g*4;
      f32x4 dx  = __builtin_amdgcn_mfma_f32_16x16x32_bf16(aX.v,  afrag, zero4, 0,0,0);
      f32x4 dy  = __builtin_amdgcn_mfma_f32_16x16x32_bf16(aY.v,  afrag, zero4, 0,0,0);
      f32x4 dxx = __builtin_amdgcn_mfma_f32_16x16x32_bf16(aXX.v, afrag, zero4, 0,0,0);
      f32x4 dyy = __builtin_amdgcn_mfma_f32_16x16x32_bf16(aYY.v, afrag, zero4, 0,0,0);
      f32x4 dxy = __builtin_amdgcn_mfma_f32_16x16x32_bf16(aXY.v, afrag, zero4, 0,0,0);
      const int base = mrow*284 + vc0;
      uint2 w;
      w.x = rhu_pack(dx[0], dx[1]);  w.y = rhu_pack(dx[2], dx[3]);
      *(uint2*)&sm.vfT[0*4544 + base] = w;
      w.x = rhu_pack(dy[0], dy[1]);  w.y = rhu_pack(dy[2], dy[3]);
      *(uint2*)&sm.vfT[1*4544 + base] = w;
      w.x = rhu_pack(dxx[0], dxx[1]); w.y = rhu_pack(dxx[2], dxx[3]);
      *(uint2*)&sm.vfT[2*4544 + base] = w;
      w.x = rhu_pack(dyy[0], dyy[1]); w.y = rhu_pack(dyy[2], dyy[3]);
      *(uint2*)&sm.vfT[3*4544 + base] = w;
      w.x = rhu_pack(dxy[0], dxy[1]); w.y = rhu_pack(dxy[2], dxy[3]);
      *(uint2*)&sm.vfT[4*4544 + base] = w;
    }
    if (wid == 0) {   // 17th tile (right pad cols 256..271)
      const int vc0 = 256 + g*4;
      f32x4 dx  = __builtin_amdgcn_mfma_f32_16x16x32_bf16(bX.v,  afrag, zero4, 0,0,0);
      f32x4 dy  = __builtin_amdgcn_mfma_f32_16x16x32_bf16(bY.v,  afrag, zero4, 0,0,0);
      f32x4 dxx = __builtin_amdgcn_mfma_f32_16x16x32_bf16(bXX.v, afrag, zero4, 0,0,0);
      f32x4 dyy = __builtin_amdgcn_mfma_f32_16x16x32_bf16(bYY.v, afrag, zero4, 0,0,0);
      f32x4 dxy = __builtin_amdgcn_mfma_f32_16x16x32_bf16(bXY.v, afrag, zero4, 0,0,0);
      const int base = mrow*284 + vc0;
      uint2 w;
      w.x = rhu_pack(dx[0], dx[1]);  w.y = rhu_pack(dx[2], dx[3]);
      *(uint2*)&sm.vfT[0*4544 + base] = w;
      w.x = rhu_pack(dy[0], dy[1]);  w.y = rhu_pack(dy[2], dy[3]);
      *(uint2*)&sm.vfT[1*4544 + base] = w;
      w.x = rhu_pack(dxx[0], dxx[1]); w.y = rhu_pack(dxx[2], dxx[3]);
      *(uint2*)&sm.vfT[2*4544 + base] = w;
      w.x = rhu_pack(dyy[0], dyy[1]); w.y = rhu_pack(dyy[2], dyy[3]);
      *(uint2*)&sm.vfT[3*4544 + base] = w;
      w.x = rhu_pack(dxy[0], dxy[1]); w.y = rhu_pack(dxy[2], dxy[3]);
      *(uint2*)&sm.vfT[4*4544 + base] = w;
    }
    __syncthreads();

    // horizontal pass + smap: one 16-col tile per wave (layout-compatible:
    // row-major u32 = (col even, col odd) pairs; row stride 142 u32)
    {
      const unsigned int* vfT32 = (const unsigned int*)sm.vfT;
      const bool rok = (r >= PAD) && (r < HW - PAD);
      float accc = 0.f;
      const int ht = wid;
      const int C0 = ht*16;
      const int w0 = mrow*142 + ((C0 + 2) >> 1) + g*4;
      UF bx, by, bxx, byy, bxy;
      #pragma unroll
      for (int j2 = 0; j2 < 4; ++j2) {
        bx.w[j2]  = vfT32[w0 + j2];
        by.w[j2]  = vfT32[w0 + j2 + 2272];
        bxx.w[j2] = vfT32[w0 + j2 + 2*2272];
        byy.w[j2] = vfT32[w0 + j2 + 3*2272];
        bxy.w[j2] = vfT32[w0 + j2 + 4*2272];
      }
      f32x4 dhx  = __builtin_amdgcn_mfma_f32_16x16x32_bf16(afrag, bx.v,  zero4, 0,0,0);
      f32x4 dhy  = __builtin_amdgcn_mfma_f32_16x16x32_bf16(afrag, by.v,  zero4, 0,0,0);
      f32x4 dhxx = __builtin_amdgcn_mfma_f32_16x16x32_bf16(afrag, bxx.v, zero4, 0,0,0);
      f32x4 dhyy = __builtin_amdgcn_mfma_f32_16x16x32_bf16(afrag, byy.v, zero4, 0,0,0);
      f32x4 dhxy = __builtin_amdgcn_mfma_f32_16x16x32_bf16(afrag, bxy.v, zero4, 0,0,0);
      #pragma unroll
      for (int i = 0; i < 4; ++i) {
        const int c = C0 + g*4 + i;
        if (rok && c >= PAD && c < HW - PAD) {
          const float hx = dhx[i], hy = dhy[i];
          const float hxx = dhxx[i], hyy = dhyy[i], hxy = dhxy[i];
          const float sx = hxx - hx*hx, sy = hyy - hy*hy, sxy = hxy - hx*hy;
          const float num = (2.f*hx*hy + C1f) * (2.f*sxy + C2f);
          const float den = (hx*hx + hy*hy + C1f) * (sx + sy + C2f);
          accc += num * __builtin_amdgcn_rcpf(den);
        }
      }
      const float n1 = (float)(HW - 2*PAD);
      acc_total += accc * __builtin_amdgcn_rcpf(n1 * n1);
    }
  }

  // block reduction
  __syncthreads();
  sm.red[t] = acc_total;
  __syncthreads();
  for (int off = 512; off > 0; off >>= 1) {
    if (t < off) sm.red[t] += sm.red[t+off];
    __syncthreads();
  }
  if (t == 0) partial[bid] = sm.red[0] * (1.f / (25.f * 128.f));
}

// ---------------- Kernel C: final deterministic reduction ----------------
__global__ __launch_bounds__(256)
void reduce_kernel(const float* __restrict__ partial, float* __restrict__ out)
{
  const int t = threadIdx.x;
  double s = 0.0;
  for (int i = t; i < NBLK; i += 256) s += (double)partial[i];
  __shared__ double red[256];
  red[t] = s;
  __syncthreads();
  for (int off = 128; off > 0; off >>= 1) {
    if (t < off) red[t] += red[t+off];
    __syncthreads();
  }
  if (t == 0) out[0] = (float)(0.5 - 0.5 * red[0]);
}

extern "C" void kernel_launch(void* const* d_in, const int* in_sizes, int n_in,
                              void* d_out, int out_size, void* d_ws, size_t ws_size,
                              hipStream_t stream) {
  const float* pred = (const float*)d_in[0];
  const float* targ = (const float*)d_in[1];
  float* out = (float*)d_out;
  float* ws = (float*)d_ws;
  float* stats   = ws;          // 512 floats
  float* partial = ws + 512;    // NBLK floats

  stats_kernel<<<256, 256, 0, stream>>>(pred, targ, stats);
  ssim_fused<<<NBLK, 1024, 0, stream>>>(pred, targ, stats, partial);
  reduce_kernel<<<1, 256, 0, stream>>>(partial, out);
}

// Round 16
// 373.015 us; speedup vs baseline: 1.7265x; 1.1403x over previous
//
#include <hip/hip_runtime.h>
#include <math.h>

#define NIMG 128
#define HW   256
#define NPX  (HW*HW)
#define NBLK (NIMG*16)   // 2048 blocks: (img, strip)

typedef float f32x4 __attribute__((ext_vector_type(4)));
typedef short bf16x8 __attribute__((ext_vector_type(8)));

__device__ __forceinline__ int refl_idx(int t) {
  return t < 0 ? -t : (t > 255 ? 510 - t : t);
}
__device__ __forceinline__ unsigned int bf16_rtn(float f) {
  unsigned int u = __float_as_uint(f);
  return (u + 0x7fffu + ((u >> 16) & 1u)) >> 16;
}
__device__ __forceinline__ unsigned int rtn_pack(float a, float b) {
  return bf16_rtn(a) | (bf16_rtn(b) << 16);
}
__device__ __forceinline__ unsigned int rhu_pack(float a, float b) {
  return ((__float_as_uint(a) + 0x8000u) >> 16) |
         ((__float_as_uint(b) + 0x8000u) & 0xffff0000u);
}

// ---------------- Kernel A: per-image mean / inv_std (ddof=1) ----------------
__global__ __launch_bounds__(256)
void stats_kernel(const float* __restrict__ pred, const float* __restrict__ targ,
                  float* __restrict__ stats)
{
  const int b = blockIdx.x;
  const int which = b >> 7;
  const int img = b & 127;
  const float4* src = (const float4*)((which ? targ : pred) + (size_t)img * NPX);
  const int t = threadIdx.x;
  double s = 0.0, s2 = 0.0;
  for (int i = t; i < NPX/4; i += 256) {
    float4 v = src[i];
    s  += (double)v.x + (double)v.y + (double)v.z + (double)v.w;
    s2 += (double)v.x*v.x + (double)v.y*v.y + (double)v.z*v.z + (double)v.w*v.w;
  }
  __shared__ double rs[256], rs2[256];
  rs[t] = s; rs2[t] = s2;
  __syncthreads();
  for (int off = 128; off > 0; off >>= 1) {
    if (t < off) { rs[t] += rs[t+off]; rs2[t] += rs2[t+off]; }
    __syncthreads();
  }
  if (t == 0) {
    const double n = (double)NPX;
    double mean = rs[0] / n;
    double var = (rs2[0] - n*mean*mean) / (n - 1.0);
    stats[(which*NIMG + img)*2 + 0] = (float)mean;
    stats[(which*NIMG + img)*2 + 1] = (float)(1.0 / sqrt(var));
  }
}

// ---------------- Fused SSIM kernel: all 25 combos per block ----------------
// Block = (img, 16-row strip). 1024 threads = 16 waves. Round-15 base +
// (1) vfT stride back to 282 u16 (141 u32, ODD -> 2-way banks on the 20
//     horizontal b32 reads); vertical writes = 2 x b32 per field.
// (2) prebuilt weight-fragment table gwfrag[25][64][4] -> afrag is one
//     ds_read_b128 per combo (replaces 8 scalar b16 reads + ~16 VALU).
// (3) vfT double-buffered -> ONE barrier per combo (50 -> 27 barriers):
//     horizontal(cb) reads buf[cb&1] while vertical(cb+1) writes the other.
struct SMEM {
  unsigned short vfT[2][5*16*282];   // 2 x 45120 B
  unsigned int  gwfrag[25][64][4];   // 25600 B
  unsigned short gwb[25][16];        //   800 B
  float red[1024];                   //  4096 B
};

__global__ __launch_bounds__(1024, 4)
void ssim_fused(const float* __restrict__ pred, const float* __restrict__ targ,
                const float* __restrict__ stats, float* __restrict__ partial)
{
  __shared__ SMEM sm;
  const int bid = blockIdx.x;
  const int img = bid >> 4, strip = bid & 15;
  const int R0 = strip * 16;
  const int t = threadIdx.x;
  const int lane = t & 63, wid = t >> 6;   // 16 waves
  const int g = lane >> 4;        // k-group 0..3
  const int mrow = lane & 15;     // A-row / B-col lane index

  // --- phase 0: gaussian taps per combo (double math, numpy-matching) ---
  if (t < 400) {
    const int c = t >> 4, tap = t & 15;
    const int ksi = c / 5, si = c % 5;
    const int ks = 5 + 2*ksi, PAD = 2 + ksi;
    const double sig = (si==0)?0.8:(si==1)?1.2:(si==2)?1.5:(si==3)?1.8:2.0;
    unsigned short w = 0;
    if (tap < ks) {
      double sum = 0.0, mine = 0.0;
      for (int a = 0; a < ks; ++a) {
        double d = (double)(a - PAD) / sig;
        double e = exp(-0.5 * d * d);
        sum += e;
        if (a == tap) mine = e;
      }
      w = (unsigned short)bf16_rtn((float)(mine / sum));
    }
    sm.gwb[c][tap] = w;
  }
  // zero vfT tail cols 272..281 of all 80 rows in BOTH buffers (horizontal
  // window over-reads with zero weight; must be non-NaN). 1600 items, strided.
  for (int i = t; i < 1600; i += 1024) {
    const int b = i / 800, rem = i % 800;
    sm.vfT[b][(rem/10)*282 + 272 + (rem%10)] = 0;
  }
  __syncthreads();

  // --- phase 0b: build per-lane weight fragments for all 25 combos ---
  // frag[c][l][j2] packs W[m][k]=g[k-m-6+PAD] for lane l: m=l&15, k=(l>>4)*8+2*j2
  for (int e = t; e < 1600; e += 1024) {
    const int c = e >> 6, l = e & 63;
    const int gg = l >> 4, mr = l & 15;
    const int PAD = 2 + c / 5;
    #pragma unroll
    for (int j2 = 0; j2 < 4; ++j2) {
      const int d0 = gg*8 + 2*j2 - mr - 6 + PAD;
      const unsigned int w0 = ((unsigned)d0 < 16u) ? (unsigned)sm.gwb[c][d0] : 0u;
      const unsigned int w1 = ((unsigned)(d0+1) < 16u) ? (unsigned)sm.gwb[c][d0+1] : 0u;
      sm.gwfrag[c][l][j2] = w0 | (w1 << 16);
    }
  }

  // --- phase 1: hoist vertical field fragments into registers (once) ---
  const float mx  = stats[img*2 + 0];
  const float ixv = stats[img*2 + 1];
  const float my  = stats[(NIMG + img)*2 + 0];
  const float iyv = stats[(NIMG + img)*2 + 1];
  const float* pp = pred + (size_t)img * NPX;
  const float* tp = targ + (size_t)img * NPX;

  union UF { unsigned int w[4]; bf16x8 v; };
  UF aX{}, aY{}, aXX{}, aYY{}, aXY{};   // tile tau = wid  (all waves)
  UF bX{}, bY{}, bXX{}, bYY{}, bXY{};   // tile tau = 16   (wave 0 only)

  auto stage_tile = [&](int tau, UF& fx, UF& fy, UF& fxx, UF& fyy, UF& fxy) {
    const int ci = refl_idx(tau*16 + mrow - 8);
    #pragma unroll
    for (int j2 = 0; j2 < 4; ++j2) {
      const int k0  = 8*g + 2*j2;
      const int ar0 = refl_idx(R0 - 6 + k0);
      const int ar1 = refl_idx(R0 - 5 + k0);
      const float p0 = pp[ar0*HW + ci], p1 = pp[ar1*HW + ci];
      const float q0 = tp[ar0*HW + ci], q1 = tp[ar1*HW + ci];
      const float xa = (p0 - mx)*ixv, xb = (p1 - mx)*ixv;
      const float ya = (q0 - my)*iyv, yb = (q1 - my)*iyv;
      fx.w[j2]  = rtn_pack(xa, xb);
      fy.w[j2]  = rtn_pack(ya, yb);
      fxx.w[j2] = rhu_pack(xa*xa, xb*xb);
      fyy.w[j2] = rhu_pack(ya*ya, yb*yb);
      fxy.w[j2] = rhu_pack(xa*ya, xb*yb);
    }
  };
  stage_tile(wid, aX, aY, aXX, aYY, aXY);
  if (wid == 0) stage_tile(16, bX, bY, bXX, bYY, bXY);

  const f32x4 zero4 = {0.f, 0.f, 0.f, 0.f};
  const float C1f = 1e-4f, C2f = 9e-4f;
  float acc_total = 0.f;
  const int r = R0 + mrow;

  // vertical pass (TRANSPOSED: field as A, W as B): lane holds row=mrow,
  // 4 consecutive cols -> 2 x b32 write per field. Row stride 282 u16.
  auto vert = [&](const bf16x8& wfrag, unsigned short* dst) {
    {
      const int vc0 = wid*16 + g*4;
      f32x4 dx  = __builtin_amdgcn_mfma_f32_16x16x32_bf16(aX.v,  wfrag, zero4, 0,0,0);
      f32x4 dy  = __builtin_amdgcn_mfma_f32_16x16x32_bf16(aY.v,  wfrag, zero4, 0,0,0);
      f32x4 dxx = __builtin_amdgcn_mfma_f32_16x16x32_bf16(aXX.v, wfrag, zero4, 0,0,0);
      f32x4 dyy = __builtin_amdgcn_mfma_f32_16x16x32_bf16(aYY.v, wfrag, zero4, 0,0,0);
      f32x4 dxy = __builtin_amdgcn_mfma_f32_16x16x32_bf16(aXY.v, wfrag, zero4, 0,0,0);
      unsigned int* p = (unsigned int*)&dst[mrow*282 + vc0];
      p[0] = rhu_pack(dx[0], dx[1]);   p[1] = rhu_pack(dx[2], dx[3]);
      p += 2256;
      p[0] = rhu_pack(dy[0], dy[1]);   p[1] = rhu_pack(dy[2], dy[3]);
      p += 2256;
      p[0] = rhu_pack(dxx[0], dxx[1]); p[1] = rhu_pack(dxx[2], dxx[3]);
      p += 2256;
      p[0] = rhu_pack(dyy[0], dyy[1]); p[1] = rhu_pack(dyy[2], dyy[3]);
      p += 2256;
      p[0] = rhu_pack(dxy[0], dxy[1]); p[1] = rhu_pack(dxy[2], dxy[3]);
    }
    if (wid == 0) {   // 17th tile (right pad cols 256..271)
      const int vc0 = 256 + g*4;
      f32x4 dx  = __builtin_amdgcn_mfma_f32_16x16x32_bf16(bX.v,  wfrag, zero4, 0,0,0);
      f32x4 dy  = __builtin_amdgcn_mfma_f32_16x16x32_bf16(bY.v,  wfrag, zero4, 0,0,0);
      f32x4 dxx = __builtin_amdgcn_mfma_f32_16x16x32_bf16(bXX.v, wfrag, zero4, 0,0,0);
      f32x4 dyy = __builtin_amdgcn_mfma_f32_16x16x32_bf16(bYY.v, wfrag, zero4, 0,0,0);
      f32x4 dxy = __builtin_amdgcn_mfma_f32_16x16x32_bf16(bXY.v, wfrag, zero4, 0,0,0);
      unsigned int* p = (unsigned int*)&dst[mrow*282 + vc0];
      p[0] = rhu_pack(dx[0], dx[1]);   p[1] = rhu_pack(dx[2], dx[3]);
      p += 2256;
      p[0] = rhu_pack(dy[0], dy[1]);   p[1] = rhu_pack(dy[2], dy[3]);
      p += 2256;
      p[0] = rhu_pack(dxx[0], dxx[1]); p[1] = rhu_pack(dxx[2], dxx[3]);
      p += 2256;
      p[0] = rhu_pack(dyy[0], dyy[1]); p[1] = rhu_pack(dyy[2], dyy[3]);
      p += 2256;
      p[0] = rhu_pack(dxy[0], dxy[1]); p[1] = rhu_pack(dxy[2], dxy[3]);
    }
  };

  __syncthreads();   // gwfrag visible

  UF frag_cur, frag_next;
  *(uint4*)frag_cur.w = *(const uint4*)&sm.gwfrag[0][lane][0];
  vert(frag_cur.v, sm.vfT[0]);
  __syncthreads();

  for (int cb = 0; cb < 25; ++cb) {
    const int PAD = 2 + cb/5;

    // horizontal pass + smap from buf[cb&1] (round-14 verified indexing)
    {
      const unsigned int* vfT32 = (const unsigned int*)sm.vfT[cb & 1];
      const bool rok = (r >= PAD) && (r < HW - PAD);
      float accc = 0.f;
      const int C0 = wid*16;
      const int w0 = mrow*141 + ((C0 + 2) >> 1) + g*4;
      UF bx, by, bxx, byy, bxy;
      #pragma unroll
      for (int j2 = 0; j2 < 4; ++j2) {
        bx.w[j2]  = vfT32[w0 + j2];
        by.w[j2]  = vfT32[w0 + j2 + 2256];
        bxx.w[j2] = vfT32[w0 + j2 + 2*2256];
        byy.w[j2] = vfT32[w0 + j2 + 3*2256];
        bxy.w[j2] = vfT32[w0 + j2 + 4*2256];
      }
      f32x4 dhx  = __builtin_amdgcn_mfma_f32_16x16x32_bf16(frag_cur.v, bx.v,  zero4, 0,0,0);
      f32x4 dhy  = __builtin_amdgcn_mfma_f32_16x16x32_bf16(frag_cur.v, by.v,  zero4, 0,0,0);
      f32x4 dhxx = __builtin_amdgcn_mfma_f32_16x16x32_bf16(frag_cur.v, bxx.v, zero4, 0,0,0);
      f32x4 dhyy = __builtin_amdgcn_mfma_f32_16x16x32_bf16(frag_cur.v, byy.v, zero4, 0,0,0);
      f32x4 dhxy = __builtin_amdgcn_mfma_f32_16x16x32_bf16(frag_cur.v, bxy.v, zero4, 0,0,0);
      #pragma unroll
      for (int i = 0; i < 4; ++i) {
        const int c = C0 + g*4 + i;
        if (rok && c >= PAD && c < HW - PAD) {
          const float hx = dhx[i], hy = dhy[i];
          const float hxx = dhxx[i], hyy = dhyy[i], hxy = dhxy[i];
          const float sx = hxx - hx*hx, sy = hyy - hy*hy, sxy = hxy - hx*hy;
          const float num = (2.f*hx*hy + C1f) * (2.f*sxy + C2f);
          const float den = (hx*hx + hy*hy + C1f) * (sx + sy + C2f);
          accc += num * __builtin_amdgcn_rcpf(den);
        }
      }
      const float n1 = (float)(HW - 2*PAD);
      acc_total += accc * __builtin_amdgcn_rcpf(n1 * n1);
    }

    // prefetch next combo's fragment + vertical into the OTHER buffer
    if (cb < 24) {
      *(uint4*)frag_next.w = *(const uint4*)&sm.gwfrag[cb + 1][lane][0];
      vert(frag_next.v, sm.vfT[(cb + 1) & 1]);
    }
    __syncthreads();   // closes: reads of buf[cb&1] AND writes of buf[(cb+1)&1]
    frag_cur = frag_next;
  }

  // block reduction
  sm.red[t] = acc_total;
  __syncthreads();
  for (int off = 512; off > 0; off >>= 1) {
    if (t < off) sm.red[t] += sm.red[t+off];
    __syncthreads();
  }
  if (t == 0) partial[bid] = sm.red[0] * (1.f / (25.f * 128.f));
}

// ---------------- Kernel C: final deterministic reduction ----------------
__global__ __launch_bounds__(256)
void reduce_kernel(const float* __restrict__ partial, float* __restrict__ out)
{
  const int t = threadIdx.x;
  double s = 0.0;
  for (int i = t; i < NBLK; i += 256) s += (double)partial[i];
  __shared__ double red[256];
  red[t] = s;
  __syncthreads();
  for (int off = 128; off > 0; off >>= 1) {
    if (t < off) red[t] += red[t+off];
    __syncthreads();
  }
  if (t == 0) out[0] = (float)(0.5 - 0.5 * red[0]);
}

extern "C" void kernel_launch(void* const* d_in, const int* in_sizes, int n_in,
                              void* d_out, int out_size, void* d_ws, size_t ws_size,
                              hipStream_t stream) {
  const float* pred = (const float*)d_in[0];
  const float* targ = (const float*)d_in[1];
  float* out = (float*)d_out;
  float* ws = (float*)d_ws;
  float* stats   = ws;          // 512 floats
  float* partial = ws + 512;    // NBLK floats

  stats_kernel<<<256, 256, 0, stream>>>(pred, targ, stats);
  ssim_fused<<<NBLK, 1024, 0, stream>>>(pred, targ, stats, partial);
  reduce_kernel<<<1, 256, 0, stream>>>(partial, out);
}

// Round 19
// 338.117 us; speedup vs baseline: 1.9047x; 1.1032x over previous
//
#include <hip/hip_runtime.h>
#include <math.h>

#define NIMG 128
#define HW   256
#define NPX  (HW*HW)
#define NBLK (NIMG*16)   // 2048 blocks: (img, strip)

typedef float f32x4 __attribute__((ext_vector_type(4)));
typedef short bf16x8 __attribute__((ext_vector_type(8)));

__device__ __forceinline__ int refl_idx(int t) {
  return t < 0 ? -t : (t > 255 ? 510 - t : t);
}
__device__ __forceinline__ unsigned int bf16_rtn(float f) {
  unsigned int u = __float_as_uint(f);
  return (u + 0x7fffu + ((u >> 16) & 1u)) >> 16;
}
__device__ __forceinline__ unsigned int rtn_pack(float a, float b) {
  return bf16_rtn(a) | (bf16_rtn(b) << 16);
}
__device__ __forceinline__ unsigned int rhu_pack(float a, float b) {
  return ((__float_as_uint(a) + 0x8000u) >> 16) |
         ((__float_as_uint(b) + 0x8000u) & 0xffff0000u);
}

// ---------------- Kernel A: per-image mean / inv_std (ddof=1) ----------------
__global__ __launch_bounds__(256)
void stats_kernel(const float* __restrict__ pred, const float* __restrict__ targ,
                  float* __restrict__ stats)
{
  const int b = blockIdx.x;
  const int which = b >> 7;
  const int img = b & 127;
  const float4* src = (const float4*)((which ? targ : pred) + (size_t)img * NPX);
  const int t = threadIdx.x;
  double s = 0.0, s2 = 0.0;
  for (int i = t; i < NPX/4; i += 256) {
    float4 v = src[i];
    s  += (double)v.x + (double)v.y + (double)v.z + (double)v.w;
    s2 += (double)v.x*v.x + (double)v.y*v.y + (double)v.z*v.z + (double)v.w*v.w;
  }
  __shared__ double rs[256], rs2[256];
  rs[t] = s; rs2[t] = s2;
  __syncthreads();
  for (int off = 128; off > 0; off >>= 1) {
    if (t < off) { rs[t] += rs[t+off]; rs2[t] += rs2[t+off]; }
    __syncthreads();
  }
  if (t == 0) {
    const double n = (double)NPX;
    double mean = rs[0] / n;
    double var = (rs2[0] - n*mean*mean) / (n - 1.0);
    stats[(which*NIMG + img)*2 + 0] = (float)mean;
    stats[(which*NIMG + img)*2 + 1] = (float)(1.0 / sqrt(var));
  }
}

// ---------------- Fused SSIM kernel: all 25 combos per block ----------------
// Block = (img, 16-row strip). 1024 threads = 16 waves. Round-16 base +
// XOR-swizzled vfT (u32 units): row stride 160 u32 (mult of 32 -> XOR
// (4*(mrow&7)) on bits 2..4 never leaves the row), col slot = vc+6 so the
// horizontal window base u32 (= mrow*160 + ht*8 + 4 + 4g) is 16B-aligned ->
// horizontal B = 5 x ds_read_b128 (was 20 b32). Writer row == reader row
// == mrow, so one XOR formula serves both sides. Vertical writes remain
// 2 x b32 per field. Double-buffered, one barrier per combo.
struct SMEM {
  unsigned int  vfT[2][12800];       // 2 x 51200 B: [f*2560 + m*160 + q] ^ x
  unsigned int  gwfrag[25][64][4];   // 25600 B
  unsigned short gwb[25][16];        //   800 B
  float red[1024];                   //  4096 B
};

__global__ __launch_bounds__(1024, 4)
void ssim_fused(const float* __restrict__ pred, const float* __restrict__ targ,
                const float* __restrict__ stats, float* __restrict__ partial)
{
  __shared__ SMEM sm;
  const int bid = blockIdx.x;
  const int img = bid >> 4, strip = bid & 15;
  const int R0 = strip * 16;
  const int t = threadIdx.x;
  const int lane = t & 63, wid = t >> 6;   // 16 waves
  const int g = lane >> 4;        // k-group 0..3
  const int mrow = lane & 15;     // A-row / B-col lane index
  const int swz = 4 * (mrow & 7); // XOR swizzle for this lane's vfT row

  // --- phase 0: gaussian taps per combo (double math, numpy-matching) ---
  if (t < 400) {
    const int c = t >> 4, tap = t & 15;
    const int ksi = c / 5, si = c % 5;
    const int ks = 5 + 2*ksi, PAD = 2 + ksi;
    const double sig = (si==0)?0.8:(si==1)?1.2:(si==2)?1.5:(si==3)?1.8:2.0;
    unsigned short w = 0;
    if (tap < ks) {
      double sum = 0.0, mine = 0.0;
      for (int a = 0; a < ks; ++a) {
        double d = (double)(a - PAD) / sig;
        double e = exp(-0.5 * d * d);
        sum += e;
        if (a == tap) mine = e;
      }
      w = (unsigned short)bf16_rtn((float)(mine / sum));
    }
    sm.gwb[c][tap] = w;
  }
  // zero u32 q=139 (slots 278/279) of every (buf, field, row): read by the
  // ht=15 b128 with zero weight; must be non-NaN. Swizzle-aware address.
  if (t < 160) {
    const int b = t / 80, rem = t % 80;
    const int f = rem >> 4, m = rem & 15;
    sm.vfT[b][(f*2560 + m*160 + 139) ^ (4*(m & 7))] = 0;
  }
  __syncthreads();

  // --- phase 0b: build per-lane weight fragments for all 25 combos ---
  for (int e = t; e < 1600; e += 1024) {
    const int c = e >> 6, l = e & 63;
    const int gg = l >> 4, mr = l & 15;
    const int PAD = 2 + c / 5;
    #pragma unroll
    for (int j2 = 0; j2 < 4; ++j2) {
      const int d0 = gg*8 + 2*j2 - mr - 6 + PAD;
      const unsigned int w0 = ((unsigned)d0 < 16u) ? (unsigned)sm.gwb[c][d0] : 0u;
      const unsigned int w1 = ((unsigned)(d0+1) < 16u) ? (unsigned)sm.gwb[c][d0+1] : 0u;
      sm.gwfrag[c][l][j2] = w0 | (w1 << 16);
    }
  }

  // --- phase 1: hoist vertical field fragments into registers (once) ---
  const float mx  = stats[img*2 + 0];
  const float ixv = stats[img*2 + 1];
  const float my  = stats[(NIMG + img)*2 + 0];
  const float iyv = stats[(NIMG + img)*2 + 1];
  const float* pp = pred + (size_t)img * NPX;
  const float* tp = targ + (size_t)img * NPX;

  union UF { unsigned int w[4]; bf16x8 v; };
  UF aX{}, aY{}, aXX{}, aYY{}, aXY{};   // tile tau = wid  (all waves)
  UF bX{}, bY{}, bXX{}, bYY{}, bXY{};   // tile tau = 16   (wave 0 only)

  auto stage_tile = [&](int tau, UF& fx, UF& fy, UF& fxx, UF& fyy, UF& fxy) {
    const int ci = refl_idx(tau*16 + mrow - 8);
    #pragma unroll
    for (int j2 = 0; j2 < 4; ++j2) {
      const int k0  = 8*g + 2*j2;
      const int ar0 = refl_idx(R0 - 6 + k0);
      const int ar1 = refl_idx(R0 - 5 + k0);
      const float p0 = pp[ar0*HW + ci], p1 = pp[ar1*HW + ci];
      const float q0 = tp[ar0*HW + ci], q1 = tp[ar1*HW + ci];
      const float xa = (p0 - mx)*ixv, xb = (p1 - mx)*ixv;
      const float ya = (q0 - my)*iyv, yb = (q1 - my)*iyv;
      fx.w[j2]  = rtn_pack(xa, xb);
      fy.w[j2]  = rtn_pack(ya, yb);
      fxx.w[j2] = rhu_pack(xa*xa, xb*xb);
      fyy.w[j2] = rhu_pack(ya*ya, yb*yb);
      fxy.w[j2] = rhu_pack(xa*ya, xb*yb);
    }
  };
  stage_tile(wid, aX, aY, aXX, aYY, aXY);
  if (wid == 0) stage_tile(16, bX, bY, bXX, bYY, bXY);

  const f32x4 zero4 = {0.f, 0.f, 0.f, 0.f};
  const float C1f = 1e-4f, C2f = 9e-4f;
  float acc_total = 0.f;
  const int r = R0 + mrow;
  const int rowbase = mrow * 160;

  // vertical pass (TRANSPOSED: field as A, W as B): lane holds row=mrow,
  // 4 consecutive cols -> 2 x b32 write per field at swizzled addresses.
  auto vert = [&](const bf16x8& wfrag, unsigned int* dst) {
    {
      const int q0 = 8*wid + 2*g + 3;   // slot (vc0+6)/2, vc0 = 16*wid+4*g
      f32x4 dx  = __builtin_amdgcn_mfma_f32_16x16x32_bf16(aX.v,  wfrag, zero4, 0,0,0);
      f32x4 dy  = __builtin_amdgcn_mfma_f32_16x16x32_bf16(aY.v,  wfrag, zero4, 0,0,0);
      f32x4 dxx = __builtin_amdgcn_mfma_f32_16x16x32_bf16(aXX.v, wfrag, zero4, 0,0,0);
      f32x4 dyy = __builtin_amdgcn_mfma_f32_16x16x32_bf16(aYY.v, wfrag, zero4, 0,0,0);
      f32x4 dxy = __builtin_amdgcn_mfma_f32_16x16x32_bf16(aXY.v, wfrag, zero4, 0,0,0);
      const int b0 = rowbase + q0;
      dst[(0*2560 + b0) ^ swz]     = rhu_pack(dx[0], dx[1]);
      dst[(0*2560 + b0 + 1) ^ swz] = rhu_pack(dx[2], dx[3]);
      dst[(1*2560 + b0) ^ swz]     = rhu_pack(dy[0], dy[1]);
      dst[(1*2560 + b0 + 1) ^ swz] = rhu_pack(dy[2], dy[3]);
      dst[(2*2560 + b0) ^ swz]     = rhu_pack(dxx[0], dxx[1]);
      dst[(2*2560 + b0 + 1) ^ swz] = rhu_pack(dxx[2], dxx[3]);
      dst[(3*2560 + b0) ^ swz]     = rhu_pack(dyy[0], dyy[1]);
      dst[(3*2560 + b0 + 1) ^ swz] = rhu_pack(dyy[2], dyy[3]);
      dst[(4*2560 + b0) ^ swz]     = rhu_pack(dxy[0], dxy[1]);
      dst[(4*2560 + b0 + 1) ^ swz] = rhu_pack(dxy[2], dxy[3]);
    }
    if (wid == 0) {   // 17th tile (slots for vc0 = 256+4g)
      const int q0 = 131 + 2*g;
      f32x4 dx  = __builtin_amdgcn_mfma_f32_16x16x32_bf16(bX.v,  wfrag, zero4, 0,0,0);
      f32x4 dy  = __builtin_amdgcn_mfma_f32_16x16x32_bf16(bY.v,  wfrag, zero4, 0,0,0);
      f32x4 dxx = __builtin_amdgcn_mfma_f32_16x16x32_bf16(bXX.v, wfrag, zero4, 0,0,0);
      f32x4 dyy = __builtin_amdgcn_mfma_f32_16x16x32_bf16(bYY.v, wfrag, zero4, 0,0,0);
      f32x4 dxy = __builtin_amdgcn_mfma_f32_16x16x32_bf16(bXY.v, wfrag, zero4, 0,0,0);
      const int b0 = rowbase + q0;
      dst[(0*2560 + b0) ^ swz]     = rhu_pack(dx[0], dx[1]);
      dst[(0*2560 + b0 + 1) ^ swz] = rhu_pack(dx[2], dx[3]);
      dst[(1*2560 + b0) ^ swz]     = rhu_pack(dy[0], dy[1]);
      dst[(1*2560 + b0 + 1) ^ swz] = rhu_pack(dy[2], dy[3]);
      dst[(2*2560 + b0) ^ swz]     = rhu_pack(dxx[0], dxx[1]);
      dst[(2*2560 + b0 + 1) ^ swz] = rhu_pack(dxx[2], dxx[3]);
      dst[(3*2560 + b0) ^ swz]     = rhu_pack(dyy[0], dyy[1]);
      dst[(3*2560 + b0 + 1) ^ swz] = rhu_pack(dyy[2], dyy[3]);
      dst[(4*2560 + b0) ^ swz]     = rhu_pack(dxy[0], dxy[1]);
      dst[(4*2560 + b0 + 1) ^ swz] = rhu_pack(dxy[2], dxy[3]);
    }
  };

  __syncthreads();   // gwfrag visible

  UF frag_cur, frag_next;
  *(uint4*)frag_cur.w = *(const uint4*)&sm.gwfrag[0][lane][0];
  vert(frag_cur.v, sm.vfT[0]);
  __syncthreads();

  for (int cb = 0; cb < 25; ++cb) {
    const int PAD = 2 + cb/5;

    // horizontal pass + smap from buf[cb&1]: 5 x b128 at swizzled base
    {
      const unsigned int* V = sm.vfT[cb & 1];
      const bool rok = (r >= PAD) && (r < HW - PAD);
      float accc = 0.f;
      const int C0 = wid*16;
      const int qb = rowbase + wid*8 + 4 + 4*g;   // 16B-aligned pre-swizzle
      UF bx, by, bxx, byy, bxy;
      *(uint4*)bx.w  = *(const uint4*)&V[(0*2560 + qb) ^ swz];
      *(uint4*)by.w  = *(const uint4*)&V[(1*2560 + qb) ^ swz];
      *(uint4*)bxx.w = *(const uint4*)&V[(2*2560 + qb) ^ swz];
      *(uint4*)byy.w = *(const uint4*)&V[(3*2560 + qb) ^ swz];
      *(uint4*)bxy.w = *(const uint4*)&V[(4*2560 + qb) ^ swz];
      f32x4 dhx  = __builtin_amdgcn_mfma_f32_16x16x32_bf16(frag_cur.v, bx.v,  zero4, 0,0,0);
      f32x4 dhy  = __builtin_amdgcn_mfma_f32_16x16x32_bf16(frag_cur.v, by.v,  zero4, 0,0,0);
      f32x4 dhxx = __builtin_amdgcn_mfma_f32_16x16x32_bf16(frag_cur.v, bxx.v, zero4, 0,0,0);
      f32x4 dhyy = __builtin_amdgcn_mfma_f32_16x16x32_bf16(frag_cur.v, byy.v, zero4, 0,0,0);
      f32x4 dhxy = __builtin_amdgcn_mfma_f32_16x16x32_bf16(frag_cur.v, bxy.v, zero4, 0,0,0);
      #pragma unroll
      for (int i = 0; i < 4; ++i) {
        const int c = C0 + g*4 + i;
        if (rok && c >= PAD && c < HW - PAD) {
          const float hx = dhx[i], hy = dhy[i];
          const float hxx = dhxx[i], hyy = dhyy[i], hxy = dhxy[i];
          const float sx = hxx - hx*hx, sy = hyy - hy*hy, sxy = hxy - hx*hy;
          const float num = (2.f*hx*hy + C1f) * (2.f*sxy + C2f);
          const float den = (hx*hx + hy*hy + C1f) * (sx + sy + C2f);
          accc += num * __builtin_amdgcn_rcpf(den);
        }
      }
      const float n1 = (float)(HW - 2*PAD);
      acc_total += accc * __builtin_amdgcn_rcpf(n1 * n1);
    }

    // prefetch next combo's fragment + vertical into the OTHER buffer
    if (cb < 24) {
      *(uint4*)frag_next.w = *(const uint4*)&sm.gwfrag[cb + 1][lane][0];
      vert(frag_next.v, sm.vfT[(cb + 1) & 1]);
    }
    __syncthreads();   // closes: reads of buf[cb&1] AND writes of buf[(cb+1)&1]
    frag_cur = frag_next;
  }

  // block reduction
  sm.red[t] = acc_total;
  __syncthreads();
  for (int off = 512; off > 0; off >>= 1) {
    if (t < off) sm.red[t] += sm.red[t+off];
    __syncthreads();
  }
  if (t == 0) partial[bid] = sm.red[0] * (1.f / (25.f * 128.f));
}

// ---------------- Kernel C: final deterministic reduction ----------------
__global__ __launch_bounds__(256)
void reduce_kernel(const float* __restrict__ partial, float* __restrict__ out)
{
  const int t = threadIdx.x;
  double s = 0.0;
  for (int i = t; i < NBLK; i += 256) s += (double)partial[i];
  __shared__ double red[256];
  red[t] = s;
  __syncthreads();
  for (int off = 128; off > 0; off >>= 1) {
    if (t < off) red[t] += red[t+off];
    __syncthreads();
  }
  if (t == 0) out[0] = (float)(0.5 - 0.5 * red[0]);
}

extern "C" void kernel_launch(void* const* d_in, const int* in_sizes, int n_in,
                              void* d_out, int out_size, void* d_ws, size_t ws_size,
                              hipStream_t stream) {
  const float* pred = (const float*)d_in[0];
  const float* targ = (const float*)d_in[1];
  float* out = (float*)d_out;
  float* ws = (float*)d_ws;
  float* stats   = ws;          // 512 floats
  float* partial = ws + 512;    // NBLK floats

  stats_kernel<<<256, 256, 0, stream>>>(pred, targ, stats);
  ssim_fused<<<NBLK, 1024, 0, stream>>>(pred, targ, stats, partial);
  reduce_kernel<<<1, 256, 0, stream>>>(partial, out);
}